// Round 1
// baseline (1177.825 us; speedup 1.0000x reference)
//
#include <hip/hip_runtime.h>
#include <math.h>

#define B_ 16
#define C_ 64
#define H_ 128
#define W_ 128
#define HW_ (H_*W_)
#define CHW_ (C_*HW_)
#define NTOT_ (B_*CHW_)

__device__ __forceinline__ float leaky(float v) { return v > 0.f ? v : 0.1f * v; }

// ---------------------------------------------------------------------------
// Dynamic kernel MLPs for both RDA convs.
// grid.x = 2*B (which,batch), block = 256.
// hid = leaky(d @ k1) [64]; kern = hid @ k2 [576] -> per-(b,c) 3x3 taps.
// ---------------------------------------------------------------------------
__global__ void k_dyn(const float* __restrict__ d,
                      const float* __restrict__ k1a, const float* __restrict__ k2a,
                      const float* __restrict__ k1b, const float* __restrict__ k2b,
                      float* __restrict__ kernA, float* __restrict__ kernB)
{
    const int rb = blockIdx.x;       // 0..31
    const int which = rb >> 4;
    const int b = rb & 15;
    const float* k1 = which ? k1b : k1a;
    const float* k2 = which ? k2b : k2a;
    float* out = which ? kernB : kernA;

    __shared__ float hid[64];
    const int tid = threadIdx.x;
    if (tid < 64) {
        float s = 0.f;
        #pragma unroll
        for (int i = 0; i < 64; ++i) s = fmaf(d[b*64 + i], k1[i*64 + tid], s);
        hid[tid] = leaky(s);
    }
    __syncthreads();
    for (int o = tid; o < 576; o += 256) {
        float s = 0.f;
        #pragma unroll
        for (int j = 0; j < 64; ++j) s = fmaf(hid[j], k2[j*576 + o], s);
        out[b*576 + o] = s;
    }
}

// ---------------------------------------------------------------------------
// Gating map: M[b,h,w] = sigmoid(sum_c X[b,c,h,w]*cw[c] + cb)
// grid = B*HW/256, block = 256. Coalesced along w for every channel plane.
// ---------------------------------------------------------------------------
__global__ void k_gate(const float* __restrict__ X, const float* __restrict__ cw,
                       const float* __restrict__ cb, float* __restrict__ M)
{
    const int idx = blockIdx.x * 256 + threadIdx.x;   // over B*HW
    const int b = idx >> 14;          // / HW_ (16384)
    const int p = idx & (HW_ - 1);
    const float* xp = X + (size_t)b * CHW_ + p;
    float s = cb[0];
    #pragma unroll
    for (int c = 0; c < 64; ++c) s = fmaf(xp[c * HW_], cw[c], s);
    M[idx] = 1.f / (1.f + __expf(-s));
}

// ---------------------------------------------------------------------------
// Fused RDA: out = leaky( leaky(depthwise3x3(X)) * M + X )
// grid = (B*C, H/2), block = 256 (2 rows x 128 cols). Taps are block-uniform
// (scalar loads); 3x3 neighborhood reads hit L1.
// ---------------------------------------------------------------------------
__global__ void k_rda(const float* __restrict__ X, const float* __restrict__ kern,
                      const float* __restrict__ M, float* __restrict__ out)
{
    const int bc = blockIdx.x;                    // b*64 + c
    const int h = blockIdx.y * 2 + (threadIdx.x >> 7);
    const int w = threadIdx.x & 127;
    const float* kp = kern + bc * 9;
    float k[9];
    #pragma unroll
    for (int t = 0; t < 9; ++t) k[t] = kp[t];

    const float* xp = X + (size_t)bc * HW_;
    float s = 0.f;
    #pragma unroll
    for (int kh = 0; kh < 3; ++kh) {
        const int hh = h + kh - 1;
        if ((unsigned)hh < (unsigned)H_) {
            #pragma unroll
            for (int kw = 0; kw < 3; ++kw) {
                const int ww = w + kw - 1;
                if ((unsigned)ww < (unsigned)W_)
                    s = fmaf(xp[hh * W_ + ww], k[kh*3 + kw], s);
            }
        }
    }
    const int b = bc >> 6;
    const float m = M[b * HW_ + h * W_ + w];
    const float xv = xp[h * W_ + w];
    out[(size_t)bc * HW_ + h * W_ + w] = leaky(leaky(s) * m + xv);
}

// ---------------------------------------------------------------------------
// Dense 3x3 conv 64->64 (+bias, optional leaky, optional residual add).
// Block: 256 thr, computes 16 out-channels x 32x32 pixels; thread = 4 px x 16 oc.
// ic chunks of 4 staged in LDS; row stride 37 -> 2-way bank aliasing (free).
// grid = (16 tiles, 4 ocg, 16 b).
// ---------------------------------------------------------------------------
template<bool LEAKY, bool RES>
__global__ __launch_bounds__(256) void k_conv3(
    const float* __restrict__ X, const float* __restrict__ Wt,
    const float* __restrict__ bias, const float* __restrict__ res,
    float* __restrict__ out)
{
    __shared__ float sIn[4][34][37];
    __shared__ float sW[16][4][12];

    const int tid = threadIdx.x;
    const int b   = blockIdx.z;
    const int ocg = blockIdx.y;          // 0..3
    const int tile = blockIdx.x;         // 0..15
    const int h0  = (tile >> 2) * 32;
    const int w0t = (tile & 3) * 32;
    const int lh  = tid >> 3;            // 0..31
    const int lw0 = (tid & 7) * 4;       // 0..28

    float acc[16][4];
    #pragma unroll
    for (int o = 0; o < 16; ++o)
        #pragma unroll
        for (int p = 0; p < 4; ++p) acc[o][p] = 0.f;

    const float* Xb = X + (size_t)b * CHW_;

    for (int c0 = 0; c0 < 64; c0 += 4) {
        // stage 4 x 34 x 34 input halo tile
        for (int idx = tid; idx < 4*34*34; idx += 256) {
            const int ic  = idx / (34*34);
            const int rem = idx - ic * (34*34);
            const int r   = rem / 34;
            const int cl  = rem - r * 34;
            const int gh  = h0 - 1 + r;
            const int gw  = w0t - 1 + cl;
            float v = 0.f;
            if ((unsigned)gh < (unsigned)H_ && (unsigned)gw < (unsigned)W_)
                v = Xb[(size_t)(c0 + ic) * HW_ + gh * W_ + gw];
            sIn[ic][r][cl] = v;
        }
        // stage 16 oc x 4 ic x 9 weights
        for (int idx = tid; idx < 576; idx += 256) {
            const int o   = idx / 36;
            const int rem = idx - o * 36;
            const int ic  = rem / 9;
            const int t   = rem - ic * 9;
            sW[o][ic][t] = Wt[(size_t)(ocg*16 + o) * (64*9) + (c0 + ic) * 9 + t];
        }
        __syncthreads();

        #pragma unroll
        for (int ic = 0; ic < 4; ++ic) {
            float in[3][6];
            #pragma unroll
            for (int kh = 0; kh < 3; ++kh)
                #pragma unroll
                for (int j = 0; j < 6; ++j)
                    in[kh][j] = sIn[ic][lh + kh][lw0 + j];
            #pragma unroll
            for (int o = 0; o < 16; ++o) {
                float w9[9];
                #pragma unroll
                for (int t = 0; t < 9; ++t) w9[t] = sW[o][ic][t];
                #pragma unroll
                for (int kh = 0; kh < 3; ++kh)
                    #pragma unroll
                    for (int kw = 0; kw < 3; ++kw) {
                        const float wt = w9[kh*3 + kw];
                        #pragma unroll
                        for (int p = 0; p < 4; ++p)
                            acc[o][p] = fmaf(in[kh][kw + p], wt, acc[o][p]);
                    }
            }
        }
        __syncthreads();
    }

    const int oh = h0 + lh;
    const int ow = w0t + lw0;
    #pragma unroll
    for (int o = 0; o < 16; ++o) {
        const float bs = bias[ocg*16 + o];
        const size_t base = (size_t)b * CHW_ + (size_t)(ocg*16 + o) * HW_ + oh * W_ + ow;
        float4 v;
        float* vp = &v.x;
        #pragma unroll
        for (int p = 0; p < 4; ++p) {
            float t = acc[o][p] + bs;
            if (LEAKY) t = leaky(t);
            if (RES)  t += res[base + p];
            vp[p] = t;
        }
        *(float4*)(out + base) = v;
    }
}

// ---------------------------------------------------------------------------
extern "C" void kernel_launch(void* const* d_in, const int* in_sizes, int n_in,
                              void* d_out, int out_size, void* d_ws, size_t ws_size,
                              hipStream_t stream)
{
    const float* x       = (const float*)d_in[0];
    const float* d       = (const float*)d_in[1];
    const float* da1_k1  = (const float*)d_in[2];
    const float* da1_k2  = (const float*)d_in[3];
    const float* da1_cw  = (const float*)d_in[4];
    const float* da1_cb  = (const float*)d_in[5];
    const float* da2_k1  = (const float*)d_in[6];
    const float* da2_k2  = (const float*)d_in[7];
    const float* da2_cw  = (const float*)d_in[8];
    const float* da2_cb  = (const float*)d_in[9];
    const float* conv1_w = (const float*)d_in[10];
    const float* conv1_b = (const float*)d_in[11];
    const float* conv2_w = (const float*)d_in[12];
    const float* conv2_b = (const float*)d_in[13];
    float* out = (float*)d_out;

    float* ws    = (float*)d_ws;
    float* buf1  = ws;                       // NTOT_ floats
    float* M     = ws + NTOT_;               // B*HW floats
    float* kernA = M + (size_t)B_ * HW_;     // 16*576
    float* kernB = kernA + 16 * 576;
    float* buf2  = out;                      // stage-B output lives in d_out

    // 1. dynamic kernels for both RDA convs
    k_dyn<<<dim3(32), dim3(256), 0, stream>>>(d, da1_k1, da1_k2, da2_k1, da2_k2,
                                              kernA, kernB);
    // 2-3. RDA conv 1:  buf1 = leaky(rda1(x))
    k_gate<<<dim3(B_*HW_/256), dim3(256), 0, stream>>>(x, da1_cw, da1_cb, M);
    k_rda<<<dim3(B_*C_, H_/2), dim3(256), 0, stream>>>(x, kernA, M, buf1);
    // 4. buf2 = leaky(conv1(buf1))
    k_conv3<true, false><<<dim3(16, 4, B_), dim3(256), 0, stream>>>(
        buf1, conv1_w, conv1_b, nullptr, buf2);
    // 5-6. RDA conv 2:  buf1 = leaky(rda2(buf2))
    k_gate<<<dim3(B_*HW_/256), dim3(256), 0, stream>>>(buf2, da2_cw, da2_cb, M);
    k_rda<<<dim3(B_*C_, H_/2), dim3(256), 0, stream>>>(buf2, kernB, M, buf1);
    // 7. out = conv2(buf1) + x
    k_conv3<false, true><<<dim3(16, 4, B_), dim3(256), 0, stream>>>(
        buf1, conv2_w, conv2_b, x, out);
}

// Round 2
// 392.678 us; speedup vs baseline: 2.9995x; 2.9995x over previous
//
#include <hip/hip_runtime.h>
#include <hip/hip_bf16.h>
#include <math.h>

#define B_ 16
#define C_ 64
#define H_ 128
#define W_ 128
#define HW_ (H_*W_)
#define CHW_ (C_*HW_)
#define NTOT_ (B_*CHW_)

typedef __attribute__((ext_vector_type(8))) short short8;
typedef __attribute__((ext_vector_type(4))) float float4v;

__device__ __forceinline__ float leaky(float v) { return v > 0.f ? v : 0.1f * v; }
__device__ __forceinline__ float b2f(__hip_bfloat16 h) { return __bfloat162float(h); }

// ---------------------------------------------------------------------------
// Dynamic kernel MLPs. out layout: kernN[b][t][c] (fp32) for lane=c access.
// ---------------------------------------------------------------------------
__global__ void k_dyn(const float* __restrict__ d,
                      const float* __restrict__ k1a, const float* __restrict__ k2a,
                      const float* __restrict__ k1b, const float* __restrict__ k2b,
                      float* __restrict__ kernA, float* __restrict__ kernB)
{
    const int rb = blockIdx.x;       // 0..31
    const int which = rb >> 4;
    const int b = rb & 15;
    const float* k1 = which ? k1b : k1a;
    const float* k2 = which ? k2b : k2a;
    float* out = which ? kernB : kernA;

    __shared__ float hid[64];
    const int tid = threadIdx.x;
    if (tid < 64) {
        float s = 0.f;
        #pragma unroll
        for (int i = 0; i < 64; ++i) s = fmaf(d[b*64 + i], k1[i*64 + tid], s);
        hid[tid] = leaky(s);
    }
    __syncthreads();
    for (int o = tid; o < 576; o += 256) {
        float s = 0.f;
        #pragma unroll
        for (int j = 0; j < 64; ++j) s = fmaf(hid[j], k2[j*576 + o], s);
        // o = c*9 + t  ->  store [t][c]
        out[b*576 + (o % 9)*64 + (o / 9)] = s;
    }
}

// ---------------------------------------------------------------------------
// Prepack conv weights: Wpk[s][oc][kk] bf16, s = t*2 + half, k = half*32+kk.
// ---------------------------------------------------------------------------
__global__ void k_prepw(const float* __restrict__ W1, const float* __restrict__ W2,
                        __hip_bfloat16* __restrict__ P1, __hip_bfloat16* __restrict__ P2)
{
    const int s = blockIdx.x;      // 0..17
    const int which = blockIdx.y;  // 0..1
    const float* W = which ? W2 : W1;
    __hip_bfloat16* P = which ? P2 : P1;
    const int t = s >> 1, half = s & 1;
    for (int idx = threadIdx.x; idx < 2048; idx += 256) {
        const int oc = idx >> 5, kk = idx & 31;
        P[s*2048 + idx] = __float2bfloat16(W[oc*576 + (half*32 + kk)*9 + t]);
    }
}

// ---------------------------------------------------------------------------
// NCHW fp32 -> NHWC bf16 (LDS transpose, coalesced both sides).
// grid (HW/64, B), block 256.
// ---------------------------------------------------------------------------
__global__ __launch_bounds__(256) void k_pre(const float* __restrict__ X,
                                             __hip_bfloat16* __restrict__ Xn)
{
    __shared__ float sT[64][65];
    const int b = blockIdx.y;
    const int p0 = blockIdx.x * 64;
    const int tid = threadIdx.x;
    #pragma unroll
    for (int i = 0; i < 16; ++i) {
        int idx = i*256 + tid;
        int c = idx >> 6, p = idx & 63;
        sT[c][p] = X[(size_t)b*CHW_ + (size_t)c*HW_ + p0 + p];
    }
    __syncthreads();
    #pragma unroll
    for (int i = 0; i < 16; ++i) {
        int idx = i*256 + tid;
        int p = idx >> 6, c = idx & 63;
        Xn[((size_t)b*HW_ + p0 + p)*64 + c] = __float2bfloat16(sT[c][p]);
    }
}

// ---------------------------------------------------------------------------
// NHWC bf16 -> NCHW fp32 + residual x. grid (HW/64, B), block 256.
// ---------------------------------------------------------------------------
__global__ __launch_bounds__(256) void k_post(const __hip_bfloat16* __restrict__ Cn,
                                              const float* __restrict__ X,
                                              float* __restrict__ Out)
{
    __shared__ float sT[64][65];
    const int b = blockIdx.y;
    const int p0 = blockIdx.x * 64;
    const int tid = threadIdx.x;
    #pragma unroll
    for (int i = 0; i < 16; ++i) {
        int idx = i*256 + tid;
        int p = idx >> 6, c = idx & 63;
        sT[c][p] = b2f(Cn[((size_t)b*HW_ + p0 + p)*64 + c]);
    }
    __syncthreads();
    #pragma unroll
    for (int i = 0; i < 16; ++i) {
        int idx = i*256 + tid;
        int c = idx >> 6, p = idx & 63;
        size_t g = (size_t)b*CHW_ + (size_t)c*HW_ + p0 + p;
        Out[g] = sT[c][p] + X[g];
    }
}

// ---------------------------------------------------------------------------
// Fused RDA in NHWC: lane = channel. Gate = wave butterfly reduction.
// out = leaky( leaky(dw3x3(X)) * sigmoid(gate) + X ).  Wave handles 8 px.
// grid = B*HW/32 blocks of 256 (4 waves).
// ---------------------------------------------------------------------------
__global__ __launch_bounds__(256) void k_rda_nhwc(
    const __hip_bfloat16* __restrict__ Xn, const float* __restrict__ kernN,
    const float* __restrict__ cw, const float* __restrict__ cb,
    __hip_bfloat16* __restrict__ Out)
{
    const int lane = threadIdx.x & 63;
    const int wv = threadIdx.x >> 6;
    const int gid = blockIdx.x * 4 + wv;     // 0 .. B*HW/8
    const int b = gid >> 11;                 // HW/8 = 2048 groups per batch
    const int rem = gid & 2047;
    const int h = rem >> 4;                  // 16 groups per row
    const int w0 = (rem & 15) * 8;

    float k9[9];
    #pragma unroll
    for (int t = 0; t < 9; ++t) k9[t] = kernN[((size_t)b*9 + t)*64 + lane];
    const float cwv = cw[lane];
    const float cbv = cb[0];

    const __hip_bfloat16* Xb = Xn + (size_t)b * HW_ * 64;
    #pragma unroll
    for (int i = 0; i < 8; ++i) {
        const int w = w0 + i;
        float s = 0.f;
        #pragma unroll
        for (int dh = -1; dh <= 1; ++dh) {
            const int hh = h + dh;
            if ((unsigned)hh >= (unsigned)H_) continue;   // wave-uniform branch
            #pragma unroll
            for (int dw = -1; dw <= 1; ++dw) {
                const int ww = w + dw;
                if ((unsigned)ww >= (unsigned)W_) continue;
                s = fmaf(b2f(Xb[((size_t)hh*W_ + ww)*64 + lane]), k9[(dh+1)*3 + (dw+1)], s);
            }
        }
        const float xc = b2f(Xb[((size_t)h*W_ + w)*64 + lane]);
        float g = xc * cwv;
        #pragma unroll
        for (int off = 32; off; off >>= 1) g += __shfl_xor(g, off);
        g += cbv;
        const float m = 1.f / (1.f + __expf(-g));
        Out[((size_t)b*HW_ + (size_t)h*W_ + w)*64 + lane] =
            __float2bfloat16(leaky(leaky(s)*m + xc));
    }
}

// ---------------------------------------------------------------------------
// Dense 3x3 conv 64->64 as implicit GEMM on MFMA bf16.
// Block: 256 thr (4 waves) -> 16x16 pixel patch (M=256) x 64 oc (N).
// K = 576 = 18 steps of 32 (9 taps x 2 halves). Halo (18x18x64 bf16) staged
// once with XOR c-chunk swizzle; K-loop is barrier-free shifted reads.
// grid (64, B).
// ---------------------------------------------------------------------------
template<bool LEAKY>
__global__ __launch_bounds__(256) void k_conv_mfma(
    const __hip_bfloat16* __restrict__ Xn, const __hip_bfloat16* __restrict__ Wpk,
    const float* __restrict__ bias, __hip_bfloat16* __restrict__ Out)
{
    __shared__ short sA[18*18*64];   // 41472 B
    const int tid = threadIdx.x;
    const int b = blockIdx.y;
    const int h0 = (blockIdx.x >> 3) * 16;
    const int w0 = (blockIdx.x & 7) * 16;

    // ---- stage halo (zero-padded), 16B granules, swizzled c-chunks
    const short* Xs = (const short*)Xn;
    for (int idx = tid; idx < 2592; idx += 256) {
        const int cc = idx & 7;
        const int w = (idx >> 3) % 18;
        const int r = idx / 144;
        const int gh = h0 - 1 + r;
        const int gw = w0 - 1 + w;
        uint4 v = make_uint4(0, 0, 0, 0);
        if ((unsigned)gh < (unsigned)H_ && (unsigned)gw < (unsigned)W_)
            v = *(const uint4*)(Xs + (((size_t)b*H_ + gh)*W_ + gw)*64 + cc*8);
        *(uint4*)(sA + ((r*18 + w)*64 + ((cc ^ (w & 7)) * 8))) = v;
    }
    __syncthreads();

    const int lane = tid & 63;
    const int wv = tid >> 6;       // wave -> patch rows [wv*4, wv*4+4)
    const int l15 = lane & 15;     // A: pixel-in-row; B/D: column (oc)
    const int lq = lane >> 4;      // quad

    float4v acc[4][4];
    #pragma unroll
    for (int i = 0; i < 4; ++i)
        #pragma unroll
        for (int j = 0; j < 4; ++j) acc[i][j] = (float4v)0.f;

    const short* Wp = (const short*)Wpk;

    #pragma unroll
    for (int s = 0; s < 18; ++s) {
        const int t = s >> 1, half = s & 1;
        const int dh = t / 3, dwx = t % 3;
        short8 afr[4], bfr[4];
        #pragma unroll
        for (int mt = 0; mt < 4; ++mt) {
            const int r = wv*4 + mt + dh;
            const int w = l15 + dwx;
            const int chunk = (half*4 + lq) ^ (w & 7);
            afr[mt] = *(const short8*)(sA + ((r*18 + w)*64 + chunk*8));
        }
        #pragma unroll
        for (int nt = 0; nt < 4; ++nt)
            bfr[nt] = *(const short8*)(Wp + ((size_t)s*2048 + (nt*16 + l15)*32 + lq*8));
        #pragma unroll
        for (int mt = 0; mt < 4; ++mt)
            #pragma unroll
            for (int nt = 0; nt < 4; ++nt)
                acc[mt][nt] = __builtin_amdgcn_mfma_f32_16x16x32_bf16(
                    afr[mt], bfr[nt], acc[mt][nt], 0, 0, 0);
    }

    // ---- epilogue: bias (+leaky), NHWC bf16 store
    #pragma unroll
    for (int nt = 0; nt < 4; ++nt) {
        const int n = nt*16 + l15;
        const float bs = bias[n];
        #pragma unroll
        for (int mt = 0; mt < 4; ++mt) {
            const int pr = wv*4 + mt;          // patch row
            #pragma unroll
            for (int rg = 0; rg < 4; ++rg) {
                const int pw = lq*4 + rg;      // D row = pixel within row-tile
                float v = acc[mt][nt][rg] + bs;
                if (LEAKY) v = leaky(v);
                Out[(((size_t)b*H_ + h0 + pr)*W_ + w0 + pw)*64 + n] =
                    __float2bfloat16(v);
            }
        }
    }
}

// ---------------------------------------------------------------------------
extern "C" void kernel_launch(void* const* d_in, const int* in_sizes, int n_in,
                              void* d_out, int out_size, void* d_ws, size_t ws_size,
                              hipStream_t stream)
{
    const float* x       = (const float*)d_in[0];
    const float* d       = (const float*)d_in[1];
    const float* da1_k1  = (const float*)d_in[2];
    const float* da1_k2  = (const float*)d_in[3];
    const float* da1_cw  = (const float*)d_in[4];
    const float* da1_cb  = (const float*)d_in[5];
    const float* da2_k1  = (const float*)d_in[6];
    const float* da2_k2  = (const float*)d_in[7];
    const float* da2_cw  = (const float*)d_in[8];
    const float* da2_cb  = (const float*)d_in[9];
    const float* conv1_w = (const float*)d_in[10];
    const float* conv1_b = (const float*)d_in[11];
    const float* conv2_w = (const float*)d_in[12];
    const float* conv2_b = (const float*)d_in[13];
    float* out = (float*)d_out;

    __hip_bfloat16* bufA = (__hip_bfloat16*)d_ws;      // NTOT_ bf16
    __hip_bfloat16* bufB = bufA + NTOT_;               // NTOT_ bf16
    float* kernA = (float*)(bufB + NTOT_);             // 16*576 fp32
    float* kernB = kernA + 16*576;
    __hip_bfloat16* wpk1 = (__hip_bfloat16*)(kernB + 16*576);  // 18*64*32
    __hip_bfloat16* wpk2 = wpk1 + 18*64*32;

    k_dyn<<<dim3(32), dim3(256), 0, stream>>>(d, da1_k1, da1_k2, da2_k1, da2_k2,
                                              kernA, kernB);
    k_prepw<<<dim3(18, 2), dim3(256), 0, stream>>>(conv1_w, conv2_w, wpk1, wpk2);
    k_pre<<<dim3(HW_/64, B_), dim3(256), 0, stream>>>(x, bufA);
    // rda1: bufA -> bufB
    k_rda_nhwc<<<dim3(B_*HW_/32), dim3(256), 0, stream>>>(bufA, kernA, da1_cw,
                                                          da1_cb, bufB);
    // conv1 (+leaky): bufB -> bufA
    k_conv_mfma<true><<<dim3(64, B_), dim3(256), 0, stream>>>(bufB, wpk1,
                                                              conv1_b, bufA);
    // rda2: bufA -> bufB
    k_rda_nhwc<<<dim3(B_*HW_/32), dim3(256), 0, stream>>>(bufA, kernB, da2_cw,
                                                          da2_cb, bufB);
    // conv2 (no leaky): bufB -> bufA
    k_conv_mfma<false><<<dim3(64, B_), dim3(256), 0, stream>>>(bufB, wpk2,
                                                               conv2_b, bufA);
    // transpose + residual
    k_post<<<dim3(HW_/64, B_), dim3(256), 0, stream>>>(bufA, x, out);
}

// Round 3
// 340.311 us; speedup vs baseline: 3.4610x; 1.1539x over previous
//
#include <hip/hip_runtime.h>
#include <hip/hip_bf16.h>
#include <math.h>

#define B_ 16
#define C_ 64
#define H_ 128
#define W_ 128
#define HW_ (H_*W_)
#define CHW_ (C_*HW_)
#define NTOT_ (B_*CHW_)

typedef __attribute__((ext_vector_type(8))) short short8;
typedef __attribute__((ext_vector_type(4))) float float4v;

__device__ __forceinline__ float leaky(float v) { return v > 0.f ? v : 0.1f * v; }
__device__ __forceinline__ float b2f(__hip_bfloat16 h) { return __bfloat162float(h); }

// ---------------------------------------------------------------------------
// Dynamic kernel MLPs, wide version: grid = 96 blocks (2 which x 16 b x 3
// chunks of 192 outputs), block = 192. hid recomputed per block (64x64, ~free).
// One output per thread -> k2 reads coalesced, 288 waves hide latency.
// out layout: kern[b][t][c] for lane=c access in k_rda.
// ---------------------------------------------------------------------------
__global__ __launch_bounds__(192) void k_dyn(
    const float* __restrict__ d,
    const float* __restrict__ k1a, const float* __restrict__ k2a,
    const float* __restrict__ k1b, const float* __restrict__ k2b,
    float* __restrict__ kernA, float* __restrict__ kernB)
{
    const int which = blockIdx.x / 48;
    const int r     = blockIdx.x % 48;
    const int b     = r / 3;
    const int chunk = r % 3;
    const float* k1 = which ? k1b : k1a;
    const float* k2 = which ? k2b : k2a;
    float* outp = which ? kernB : kernA;

    __shared__ float hid[64];
    const int tid = threadIdx.x;
    if (tid < 64) {
        float s = 0.f;
        #pragma unroll
        for (int i = 0; i < 64; ++i) s = fmaf(d[b*64 + i], k1[i*64 + tid], s);
        hid[tid] = leaky(s);
    }
    __syncthreads();
    const int o = chunk * 192 + tid;       // 0..575
    float s = 0.f;
    #pragma unroll
    for (int j = 0; j < 64; ++j) s = fmaf(hid[j], k2[j*576 + o], s);
    outp[b*576 + (o % 9)*64 + (o / 9)] = s;
}

// ---------------------------------------------------------------------------
// Prepack conv weights: Wpk[s][oc][kk] bf16, s = t*2 + half, k = half*32+kk.
// ---------------------------------------------------------------------------
__global__ void k_prepw(const float* __restrict__ W1, const float* __restrict__ W2,
                        __hip_bfloat16* __restrict__ P1, __hip_bfloat16* __restrict__ P2)
{
    const int s = blockIdx.x;      // 0..17
    const int which = blockIdx.y;  // 0..1
    const float* W = which ? W2 : W1;
    __hip_bfloat16* P = which ? P2 : P1;
    const int t = s >> 1, half = s & 1;
    for (int idx = threadIdx.x; idx < 2048; idx += 256) {
        const int oc = idx >> 5, kk = idx & 31;
        P[s*2048 + idx] = __float2bfloat16(W[oc*576 + (half*32 + kk)*9 + t]);
    }
}

// ---------------------------------------------------------------------------
// NCHW fp32 -> NHWC bf16 (LDS transpose, coalesced both sides).
// grid (HW/64, B), block 256.
// ---------------------------------------------------------------------------
__global__ __launch_bounds__(256) void k_pre(const float* __restrict__ X,
                                             __hip_bfloat16* __restrict__ Xn)
{
    __shared__ float sT[64][65];
    const int b = blockIdx.y;
    const int p0 = blockIdx.x * 64;
    const int tid = threadIdx.x;
    #pragma unroll
    for (int i = 0; i < 16; ++i) {
        int idx = i*256 + tid;
        int c = idx >> 6, p = idx & 63;
        sT[c][p] = X[(size_t)b*CHW_ + (size_t)c*HW_ + p0 + p];
    }
    __syncthreads();
    #pragma unroll
    for (int i = 0; i < 16; ++i) {
        int idx = i*256 + tid;
        int p = idx >> 6, c = idx & 63;
        Xn[((size_t)b*HW_ + p0 + p)*64 + c] = __float2bfloat16(sT[c][p]);
    }
}

// ---------------------------------------------------------------------------
// Fused RDA in NHWC: lane = channel. Gate = wave butterfly reduction.
// out = leaky( leaky(dw3x3(X)) * sigmoid(gate) + X ).  Wave handles 8 px.
// grid = B*HW/32 blocks of 256 (4 waves).
// ---------------------------------------------------------------------------
__global__ __launch_bounds__(256) void k_rda_nhwc(
    const __hip_bfloat16* __restrict__ Xn, const float* __restrict__ kernN,
    const float* __restrict__ cw, const float* __restrict__ cb,
    __hip_bfloat16* __restrict__ Out)
{
    const int lane = threadIdx.x & 63;
    const int wv = threadIdx.x >> 6;
    const int gid = blockIdx.x * 4 + wv;     // 0 .. B*HW/8
    const int b = gid >> 11;                 // HW/8 = 2048 groups per batch
    const int rem = gid & 2047;
    const int h = rem >> 4;                  // 16 groups per row
    const int w0 = (rem & 15) * 8;

    float k9[9];
    #pragma unroll
    for (int t = 0; t < 9; ++t) k9[t] = kernN[((size_t)b*9 + t)*64 + lane];
    const float cwv = cw[lane];
    const float cbv = cb[0];

    const __hip_bfloat16* Xb = Xn + (size_t)b * HW_ * 64;
    #pragma unroll
    for (int i = 0; i < 8; ++i) {
        const int w = w0 + i;
        float s = 0.f;
        #pragma unroll
        for (int dh = -1; dh <= 1; ++dh) {
            const int hh = h + dh;
            if ((unsigned)hh >= (unsigned)H_) continue;   // wave-uniform branch
            #pragma unroll
            for (int dw = -1; dw <= 1; ++dw) {
                const int ww = w + dw;
                if ((unsigned)ww >= (unsigned)W_) continue;
                s = fmaf(b2f(Xb[((size_t)hh*W_ + ww)*64 + lane]), k9[(dh+1)*3 + (dw+1)], s);
            }
        }
        const float xc = b2f(Xb[((size_t)h*W_ + w)*64 + lane]);
        float g = xc * cwv;
        #pragma unroll
        for (int off = 32; off; off >>= 1) g += __shfl_xor(g, off);
        g += cbv;
        const float m = 1.f / (1.f + __expf(-g));
        Out[((size_t)b*HW_ + (size_t)h*W_ + w)*64 + lane] =
            __float2bfloat16(leaky(leaky(s)*m + xc));
    }
}

// ---------------------------------------------------------------------------
// Dense 3x3 conv 64->64 as implicit GEMM on MFMA bf16.
// Block: 256 thr (4 waves) -> 16x16 pixel patch (M=256) x 64 oc (N).
// K = 576 = 18 steps of 32 (9 taps x 2 halves). Halo (18x18x64 bf16) staged
// once with XOR c-chunk swizzle; K-loop is barrier-free shifted reads.
// MODE 0: +leaky, NHWC bf16 out.  MODE 1: +x residual, NCHW fp32 out
// (fuses the old k_post: each lane's 4 rg-pixels are w-contiguous -> float4).
// grid (64, B).
// ---------------------------------------------------------------------------
template<int MODE>
__global__ __launch_bounds__(256) void k_conv_mfma(
    const __hip_bfloat16* __restrict__ Xn, const __hip_bfloat16* __restrict__ Wpk,
    const float* __restrict__ bias, const float* __restrict__ Xres,
    __hip_bfloat16* __restrict__ OutN, float* __restrict__ OutF)
{
    __shared__ short sA[18*18*64];   // 41472 B
    const int tid = threadIdx.x;
    const int b = blockIdx.y;
    const int h0 = (blockIdx.x >> 3) * 16;
    const int w0 = (blockIdx.x & 7) * 16;

    // ---- stage halo (zero-padded), 16B granules, swizzled c-chunks
    const short* Xs = (const short*)Xn;
    for (int idx = tid; idx < 2592; idx += 256) {
        const int cc = idx & 7;
        const int w = (idx >> 3) % 18;
        const int r = idx / 144;
        const int gh = h0 - 1 + r;
        const int gw = w0 - 1 + w;
        uint4 v = make_uint4(0, 0, 0, 0);
        if ((unsigned)gh < (unsigned)H_ && (unsigned)gw < (unsigned)W_)
            v = *(const uint4*)(Xs + (((size_t)b*H_ + gh)*W_ + gw)*64 + cc*8);
        *(uint4*)(sA + ((r*18 + w)*64 + ((cc ^ (w & 7)) * 8))) = v;
    }
    __syncthreads();

    const int lane = tid & 63;
    const int wv = tid >> 6;       // wave -> patch rows [wv*4, wv*4+4)
    const int l15 = lane & 15;     // A: pixel-in-row; B/D: column (oc)
    const int lq = lane >> 4;      // quad

    float4v acc[4][4];
    #pragma unroll
    for (int i = 0; i < 4; ++i)
        #pragma unroll
        for (int j = 0; j < 4; ++j) acc[i][j] = (float4v)0.f;

    const short* Wp = (const short*)Wpk;

    #pragma unroll
    for (int s = 0; s < 18; ++s) {
        const int t = s >> 1, half = s & 1;
        const int dh = t / 3, dwx = t % 3;
        short8 afr[4], bfr[4];
        #pragma unroll
        for (int mt = 0; mt < 4; ++mt) {
            const int r = wv*4 + mt + dh;
            const int w = l15 + dwx;
            const int chunk = (half*4 + lq) ^ (w & 7);
            afr[mt] = *(const short8*)(sA + ((r*18 + w)*64 + chunk*8));
        }
        #pragma unroll
        for (int nt = 0; nt < 4; ++nt)
            bfr[nt] = *(const short8*)(Wp + ((size_t)s*2048 + (nt*16 + l15)*32 + lq*8));
        #pragma unroll
        for (int mt = 0; mt < 4; ++mt)
            #pragma unroll
            for (int nt = 0; nt < 4; ++nt)
                acc[mt][nt] = __builtin_amdgcn_mfma_f32_16x16x32_bf16(
                    afr[mt], bfr[nt], acc[mt][nt], 0, 0, 0);
    }

    // ---- epilogue
    #pragma unroll
    for (int nt = 0; nt < 4; ++nt) {
        const int n = nt*16 + l15;          // oc
        const float bs = bias[n];
        #pragma unroll
        for (int mt = 0; mt < 4; ++mt) {
            const int pr = wv*4 + mt;       // patch row
            if (MODE == 0) {
                #pragma unroll
                for (int rg = 0; rg < 4; ++rg) {
                    const int pw = lq*4 + rg;
                    float v = leaky(acc[mt][nt][rg] + bs);
                    OutN[(((size_t)b*H_ + h0 + pr)*W_ + w0 + pw)*64 + n] =
                        __float2bfloat16(v);
                }
            } else {
                // NCHW fp32 + residual; lane's 4 pixels are w-contiguous
                const size_t base = ((size_t)(b*64 + n)*H_ + h0 + pr)*W_ + w0 + lq*4;
                const float4 xr = *(const float4*)(Xres + base);
                float4 v;
                v.x = acc[mt][nt][0] + bs + xr.x;
                v.y = acc[mt][nt][1] + bs + xr.y;
                v.z = acc[mt][nt][2] + bs + xr.z;
                v.w = acc[mt][nt][3] + bs + xr.w;
                *(float4*)(OutF + base) = v;
            }
        }
    }
}

// ---------------------------------------------------------------------------
extern "C" void kernel_launch(void* const* d_in, const int* in_sizes, int n_in,
                              void* d_out, int out_size, void* d_ws, size_t ws_size,
                              hipStream_t stream)
{
    const float* x       = (const float*)d_in[0];
    const float* d       = (const float*)d_in[1];
    const float* da1_k1  = (const float*)d_in[2];
    const float* da1_k2  = (const float*)d_in[3];
    const float* da1_cw  = (const float*)d_in[4];
    const float* da1_cb  = (const float*)d_in[5];
    const float* da2_k1  = (const float*)d_in[6];
    const float* da2_k2  = (const float*)d_in[7];
    const float* da2_cw  = (const float*)d_in[8];
    const float* da2_cb  = (const float*)d_in[9];
    const float* conv1_w = (const float*)d_in[10];
    const float* conv1_b = (const float*)d_in[11];
    const float* conv2_w = (const float*)d_in[12];
    const float* conv2_b = (const float*)d_in[13];
    float* out = (float*)d_out;

    __hip_bfloat16* bufA = (__hip_bfloat16*)d_ws;      // NTOT_ bf16
    __hip_bfloat16* bufB = bufA + NTOT_;               // NTOT_ bf16
    float* kernA = (float*)(bufB + NTOT_);             // 16*576 fp32
    float* kernB = kernA + 16*576;
    __hip_bfloat16* wpk1 = (__hip_bfloat16*)(kernB + 16*576);  // 18*64*32
    __hip_bfloat16* wpk2 = wpk1 + 18*64*32;

    k_dyn<<<dim3(96), dim3(192), 0, stream>>>(d, da1_k1, da1_k2, da2_k1, da2_k2,
                                              kernA, kernB);
    k_prepw<<<dim3(18, 2), dim3(256), 0, stream>>>(conv1_w, conv2_w, wpk1, wpk2);
    k_pre<<<dim3(HW_/64, B_), dim3(256), 0, stream>>>(x, bufA);
    // rda1: bufA -> bufB
    k_rda_nhwc<<<dim3(B_*HW_/32), dim3(256), 0, stream>>>(bufA, kernA, da1_cw,
                                                          da1_cb, bufB);
    // conv1 (+leaky): bufB -> bufA (NHWC bf16)
    k_conv_mfma<0><<<dim3(64, B_), dim3(256), 0, stream>>>(
        bufB, wpk1, conv1_b, nullptr, bufA, nullptr);
    // rda2: bufA -> bufB
    k_rda_nhwc<<<dim3(B_*HW_/32), dim3(256), 0, stream>>>(bufA, kernB, da2_cw,
                                                          da2_cb, bufB);
    // conv2 + x residual -> out (NCHW fp32), k_post fused away
    k_conv_mfma<1><<<dim3(64, B_), dim3(256), 0, stream>>>(
        bufB, wpk2, conv2_b, x, nullptr, out);
}

// Round 4
// 279.521 us; speedup vs baseline: 4.2137x; 1.2175x over previous
//
#include <hip/hip_runtime.h>
#include <hip/hip_bf16.h>
#include <math.h>

#define B_ 16
#define C_ 64
#define H_ 128
#define W_ 128
#define HW_ (H_*W_)
#define CHW_ (C_*HW_)
#define NTOT_ (B_*CHW_)

typedef __attribute__((ext_vector_type(8))) short short8;
typedef __attribute__((ext_vector_type(4))) float float4v;

__device__ __forceinline__ float leaky(float v) { return v > 0.f ? v : 0.1f * v; }
__device__ __forceinline__ float b2f(__hip_bfloat16 h) { return __bfloat162float(h); }

// ---------------------------------------------------------------------------
// Dynamic kernel MLPs, wide: 96 blocks (2 which x 16 b x 3 chunks of 192).
// out layout: kern[b][t][c] for lane=c access in k_rda.
// ---------------------------------------------------------------------------
__global__ __launch_bounds__(192) void k_dyn(
    const float* __restrict__ d,
    const float* __restrict__ k1a, const float* __restrict__ k2a,
    const float* __restrict__ k1b, const float* __restrict__ k2b,
    float* __restrict__ kernA, float* __restrict__ kernB)
{
    const int which = blockIdx.x / 48;
    const int r     = blockIdx.x % 48;
    const int b     = r / 3;
    const int chunk = r % 3;
    const float* k1 = which ? k1b : k1a;
    const float* k2 = which ? k2b : k2a;
    float* outp = which ? kernB : kernA;

    __shared__ float hid[64];
    const int tid = threadIdx.x;
    if (tid < 64) {
        float s = 0.f;
        #pragma unroll
        for (int i = 0; i < 64; ++i) s = fmaf(d[b*64 + i], k1[i*64 + tid], s);
        hid[tid] = leaky(s);
    }
    __syncthreads();
    const int o = chunk * 192 + tid;       // 0..575
    float s = 0.f;
    #pragma unroll
    for (int j = 0; j < 64; ++j) s = fmaf(hid[j], k2[j*576 + o], s);
    outp[b*576 + (o % 9)*64 + (o / 9)] = s;
}

// ---------------------------------------------------------------------------
// Prepack conv weights: Wpk[s][oc][kk] bf16, s = t*2 + half, k = half*32+kk.
// ---------------------------------------------------------------------------
__global__ void k_prepw(const float* __restrict__ W1, const float* __restrict__ W2,
                        __hip_bfloat16* __restrict__ P1, __hip_bfloat16* __restrict__ P2)
{
    const int s = blockIdx.x;      // 0..17
    const int which = blockIdx.y;  // 0..1
    const float* W = which ? W2 : W1;
    __hip_bfloat16* P = which ? P2 : P1;
    const int t = s >> 1, half = s & 1;
    for (int idx = threadIdx.x; idx < 2048; idx += 256) {
        const int oc = idx >> 5, kk = idx & 31;
        P[s*2048 + idx] = __float2bfloat16(W[oc*576 + (half*32 + kk)*9 + t]);
    }
}

// ---------------------------------------------------------------------------
// NCHW fp32 -> NHWC bf16 + fused rda1 gate: G1[p] = sigmoid(sum_c x*cw + cb).
// grid (HW/64, B), block 256.
// ---------------------------------------------------------------------------
__global__ __launch_bounds__(256) void k_pre(const float* __restrict__ X,
                                             const float* __restrict__ cw,
                                             const float* __restrict__ cb,
                                             __hip_bfloat16* __restrict__ Xn,
                                             float* __restrict__ G1)
{
    __shared__ float sT[64][65];
    __shared__ float pG[4][64];
    const int b = blockIdx.y;
    const int p0 = blockIdx.x * 64;
    const int tid = threadIdx.x;
    #pragma unroll
    for (int i = 0; i < 16; ++i) {
        int idx = i*256 + tid;
        int c = idx >> 6, p = idx & 63;
        sT[c][p] = X[(size_t)b*CHW_ + (size_t)c*HW_ + p0 + p];
    }
    __syncthreads();
    #pragma unroll
    for (int i = 0; i < 16; ++i) {
        int idx = i*256 + tid;
        int p = idx >> 6, c = idx & 63;
        Xn[((size_t)b*HW_ + p0 + p)*64 + c] = __float2bfloat16(sT[c][p]);
    }
    // gate partials: thread = (cg, p)
    const int cg = tid >> 6, p = tid & 63;
    float part = 0.f;
    #pragma unroll
    for (int c = 0; c < 16; ++c) part = fmaf(sT[cg*16 + c][p], cw[cg*16 + c], part);
    pG[cg][p] = part;
    __syncthreads();
    if (tid < 64) {
        float g = pG[0][tid] + pG[1][tid] + pG[2][tid] + pG[3][tid] + cb[0];
        G1[(size_t)b*HW_ + p0 + tid] = 1.f / (1.f + __expf(-g));
    }
}

// ---------------------------------------------------------------------------
// Fused RDA in NHWC, rolling-window version. lane = channel; wave = 8 px row
// segment. Gate M is precomputed (G). 3x10 tap window loaded once (30 loads),
// then 72 register FMAs; boundary checks wave-uniform.
// out = leaky( leaky(dw3x3(X)) * G + X ).  grid = B*HW/32 blocks of 256.
// ---------------------------------------------------------------------------
__global__ __launch_bounds__(256) void k_rda_nhwc(
    const __hip_bfloat16* __restrict__ Xn, const float* __restrict__ kernN,
    const float* __restrict__ G, __hip_bfloat16* __restrict__ Out)
{
    const int lane = threadIdx.x & 63;
    const int wv = threadIdx.x >> 6;
    const int gid = blockIdx.x * 4 + wv;     // 0 .. B*HW/8
    const int b = gid >> 11;
    const int rem = gid & 2047;
    const int h = rem >> 4;
    const int w0 = (rem & 15) * 8;

    float k9[9];
    #pragma unroll
    for (int t = 0; t < 9; ++t) k9[t] = kernN[((size_t)b*9 + t)*64 + lane];

    const __hip_bfloat16* Xb = Xn + (size_t)b * HW_ * 64 + lane;
    float r[3][10];
    #pragma unroll
    for (int dh = 0; dh < 3; ++dh) {
        const int hh = h - 1 + dh;
        if ((unsigned)hh < (unsigned)H_) {                 // wave-uniform
            const __hip_bfloat16* rp = Xb + ((size_t)hh*W_ + w0) * 64;
            r[dh][0] = (w0 > 0) ? b2f(rp[-64]) : 0.f;
            #pragma unroll
            for (int j = 1; j < 9; ++j) r[dh][j] = b2f(rp[(j-1)*64]);
            r[dh][9] = (w0 + 8 < W_) ? b2f(rp[8*64]) : 0.f;
        } else {
            #pragma unroll
            for (int j = 0; j < 10; ++j) r[dh][j] = 0.f;
        }
    }

    const float* Gp = G + (size_t)b*HW_ + (size_t)h*W_ + w0;
    __hip_bfloat16* Op = Out + ((size_t)b*HW_ + (size_t)h*W_ + w0)*64 + lane;
    #pragma unroll
    for (int i = 0; i < 8; ++i) {
        float s = 0.f;
        #pragma unroll
        for (int dh = 0; dh < 3; ++dh)
            #pragma unroll
            for (int dw = 0; dw < 3; ++dw)
                s = fmaf(r[dh][i + dw], k9[dh*3 + dw], s);
        const float xc = r[1][i + 1];
        const float m = Gp[i];
        Op[i*64] = __float2bfloat16(leaky(leaky(s)*m + xc));
    }
}

// ---------------------------------------------------------------------------
// Dense 3x3 conv 64->64 as implicit GEMM on MFMA bf16.
// Block: 256 thr (4 waves) -> 16x16 px (M=256) x 64 oc (N). K = 18 x 32.
// Halo staged once, XOR c-chunk swizzle, barrier-free K-loop.
// MODE 0: +leaky, NHWC bf16 out, + fused rda2 gate G2 (1 shfl/px).
// MODE 1: +x residual, NCHW fp32 out (k_post fused).
// grid (64, B).
// ---------------------------------------------------------------------------
template<int MODE>
__global__ __launch_bounds__(256) void k_conv_mfma(
    const __hip_bfloat16* __restrict__ Xn, const __hip_bfloat16* __restrict__ Wpk,
    const float* __restrict__ bias, const float* __restrict__ Xres,
    const float* __restrict__ Gcw, const float* __restrict__ Gcb,
    __hip_bfloat16* __restrict__ OutN, float* __restrict__ OutF,
    float* __restrict__ G2)
{
    __shared__ short sA[18*18*64];   // 41472 B
    const int tid = threadIdx.x;
    const int b = blockIdx.y;
    const int h0 = (blockIdx.x >> 3) * 16;
    const int w0 = (blockIdx.x & 7) * 16;

    const short* Xs = (const short*)Xn;
    for (int idx = tid; idx < 2592; idx += 256) {
        const int cc = idx & 7;
        const int w = (idx >> 3) % 18;
        const int r = idx / 144;
        const int gh = h0 - 1 + r;
        const int gw = w0 - 1 + w;
        uint4 v = make_uint4(0, 0, 0, 0);
        if ((unsigned)gh < (unsigned)H_ && (unsigned)gw < (unsigned)W_)
            v = *(const uint4*)(Xs + (((size_t)b*H_ + gh)*W_ + gw)*64 + cc*8);
        *(uint4*)(sA + ((r*18 + w)*64 + ((cc ^ (w & 7)) * 8))) = v;
    }
    __syncthreads();

    const int lane = tid & 63;
    const int wv = tid >> 6;
    const int l15 = lane & 15;
    const int lq = lane >> 4;

    float4v acc[4][4];
    #pragma unroll
    for (int i = 0; i < 4; ++i)
        #pragma unroll
        for (int j = 0; j < 4; ++j) acc[i][j] = (float4v)0.f;

    const short* Wp = (const short*)Wpk;

    #pragma unroll
    for (int s = 0; s < 18; ++s) {
        const int t = s >> 1, half = s & 1;
        const int dh = t / 3, dwx = t % 3;
        short8 afr[4], bfr[4];
        #pragma unroll
        for (int mt = 0; mt < 4; ++mt) {
            const int r = wv*4 + mt + dh;
            const int w = l15 + dwx;
            const int chunk = (half*4 + lq) ^ (w & 7);
            afr[mt] = *(const short8*)(sA + ((r*18 + w)*64 + chunk*8));
        }
        #pragma unroll
        for (int nt = 0; nt < 4; ++nt)
            bfr[nt] = *(const short8*)(Wp + ((size_t)s*2048 + (nt*16 + l15)*32 + lq*8));
        #pragma unroll
        for (int mt = 0; mt < 4; ++mt)
            #pragma unroll
            for (int nt = 0; nt < 4; ++nt)
                acc[mt][nt] = __builtin_amdgcn_mfma_f32_16x16x32_bf16(
                    afr[mt], bfr[nt], acc[mt][nt], 0, 0, 0);
    }

    // ---- epilogue
    float bs[4], cwv[4], cbv = 0.f;
    #pragma unroll
    for (int nt = 0; nt < 4; ++nt) bs[nt] = bias[nt*16 + l15];
    if (MODE == 0) {
        #pragma unroll
        for (int nt = 0; nt < 4; ++nt) cwv[nt] = Gcw[nt*16 + l15];
        cbv = Gcb[0];
    }

    #pragma unroll
    for (int mt = 0; mt < 4; ++mt) {
        const int pr = wv*4 + mt;
        if (MODE == 0) {
            float vv[4][4];
            #pragma unroll
            for (int nt = 0; nt < 4; ++nt)
                #pragma unroll
                for (int rg = 0; rg < 4; ++rg)
                    vv[nt][rg] = leaky(acc[mt][nt][rg] + bs[nt]);
            #pragma unroll
            for (int nt = 0; nt < 4; ++nt) {
                const int n = nt*16 + l15;
                #pragma unroll
                for (int rg = 0; rg < 4; ++rg) {
                    const int pw = lq*4 + rg;
                    OutN[(((size_t)b*H_ + h0 + pr)*W_ + w0 + pw)*64 + n] =
                        __float2bfloat16(vv[nt][rg]);
                }
            }
            // fused rda2 gate: reduce 64 oc = 4 nt (in-lane) x 16 l15 (shfl)
            #pragma unroll
            for (int rg = 0; rg < 4; ++rg) {
                float p = vv[0][rg]*cwv[0] + vv[1][rg]*cwv[1]
                        + vv[2][rg]*cwv[2] + vv[3][rg]*cwv[3];
                p += __shfl_xor(p, 1);
                p += __shfl_xor(p, 2);
                p += __shfl_xor(p, 4);
                p += __shfl_xor(p, 8);
                if (l15 == 0)
                    G2[(size_t)b*HW_ + (size_t)(h0 + pr)*W_ + w0 + lq*4 + rg] =
                        1.f / (1.f + __expf(-(p + cbv)));
            }
        } else {
            #pragma unroll
            for (int nt = 0; nt < 4; ++nt) {
                const int n = nt*16 + l15;
                const size_t base = ((size_t)(b*64 + n)*H_ + h0 + pr)*W_ + w0 + lq*4;
                const float4 xr = *(const float4*)(Xres + base);
                float4 v;
                v.x = acc[mt][nt][0] + bs[nt] + xr.x;
                v.y = acc[mt][nt][1] + bs[nt] + xr.y;
                v.z = acc[mt][nt][2] + bs[nt] + xr.z;
                v.w = acc[mt][nt][3] + bs[nt] + xr.w;
                *(float4*)(OutF + base) = v;
            }
        }
    }
}

// ---------------------------------------------------------------------------
extern "C" void kernel_launch(void* const* d_in, const int* in_sizes, int n_in,
                              void* d_out, int out_size, void* d_ws, size_t ws_size,
                              hipStream_t stream)
{
    const float* x       = (const float*)d_in[0];
    const float* d       = (const float*)d_in[1];
    const float* da1_k1  = (const float*)d_in[2];
    const float* da1_k2  = (const float*)d_in[3];
    const float* da1_cw  = (const float*)d_in[4];
    const float* da1_cb  = (const float*)d_in[5];
    const float* da2_k1  = (const float*)d_in[6];
    const float* da2_k2  = (const float*)d_in[7];
    const float* da2_cw  = (const float*)d_in[8];
    const float* da2_cb  = (const float*)d_in[9];
    const float* conv1_w = (const float*)d_in[10];
    const float* conv1_b = (const float*)d_in[11];
    const float* conv2_w = (const float*)d_in[12];
    const float* conv2_b = (const float*)d_in[13];
    float* out = (float*)d_out;

    __hip_bfloat16* bufA = (__hip_bfloat16*)d_ws;      // NTOT_ bf16
    __hip_bfloat16* bufB = bufA + NTOT_;               // NTOT_ bf16
    float* kernA = (float*)(bufB + NTOT_);             // 16*576 fp32
    float* kernB = kernA + 16*576;
    __hip_bfloat16* wpk1 = (__hip_bfloat16*)(kernB + 16*576);  // 18*64*32
    __hip_bfloat16* wpk2 = wpk1 + 18*64*32;
    float* G1 = (float*)(wpk2 + 18*64*32);             // B*HW fp32
    float* G2 = G1 + (size_t)B_*HW_;                   // B*HW fp32

    k_dyn<<<dim3(96), dim3(192), 0, stream>>>(d, da1_k1, da1_k2, da2_k1, da2_k2,
                                              kernA, kernB);
    k_prepw<<<dim3(18, 2), dim3(256), 0, stream>>>(conv1_w, conv2_w, wpk1, wpk2);
    // pre + rda1 gate
    k_pre<<<dim3(HW_/64, B_), dim3(256), 0, stream>>>(x, da1_cw, da1_cb, bufA, G1);
    // rda1: bufA -> bufB
    k_rda_nhwc<<<dim3(B_*HW_/32), dim3(256), 0, stream>>>(bufA, kernA, G1, bufB);
    // conv1 (+leaky, + rda2 gate): bufB -> bufA (NHWC bf16), G2
    k_conv_mfma<0><<<dim3(64, B_), dim3(256), 0, stream>>>(
        bufB, wpk1, conv1_b, nullptr, da2_cw, da2_cb, bufA, nullptr, G2);
    // rda2: bufA -> bufB
    k_rda_nhwc<<<dim3(B_*HW_/32), dim3(256), 0, stream>>>(bufA, kernB, G2, bufB);
    // conv2 + x residual -> out (NCHW fp32)
    k_conv_mfma<1><<<dim3(64, B_), dim3(256), 0, stream>>>(
        bufB, wpk2, conv2_b, x, nullptr, nullptr, nullptr, out, nullptr);
}